// Round 7
// baseline (178.033 us; speedup 1.0000x reference)
//
#include <hip/hip_runtime.h>

// ContextualAttention: out[b,c,p] = sum_k K[b,k,c] * softmax_k( K[b,:,:] @ F[b,:,p] )
// K = rowwise-normalized (F^T + eps). Flash-style fusion, bf16 MFMA, f32 accum.
// Round 6: producer counted-vmcnt pipeline (T4): 3-buffer KA ring, stage tile
//   i+2 each phase, barrier waits vmcnt(4) (tile i+1 done, i+2 in flight).
//   GEMM1 accumulator chains split 8->4 deep. Consumer as round 5.

#define BATCH 8
#define CH 256
#define NPIX 4096
#define EPSV 1e-7f
#define L2E 1.4426950408889634f

using bf16x8 = __attribute__((ext_vector_type(8))) __bf16;
using bf16x4 = __attribute__((ext_vector_type(4))) __bf16;
using f32x4  = __attribute__((ext_vector_type(4))) float;

__device__ __forceinline__ void gload16(const void* g, void* l) {
  __builtin_amdgcn_global_load_lds(
      (const __attribute__((address_space(1))) unsigned int*)g,
      (__attribute__((address_space(3))) unsigned int*)l, 16, 0, 0);
}

// producer steady-state barrier: oldest staged tile forced complete (vmcnt<=4
// leaves only the newest tile's 4 loads in flight); P writes drained (lgkm).
__device__ __forceinline__ void barrier_vm4() {
  asm volatile("s_waitcnt vmcnt(4) lgkmcnt(0)\n"
               "s_barrier" ::: "memory");
}
__device__ __forceinline__ void barrier_full() {
  asm volatile("s_waitcnt vmcnt(0) lgkmcnt(0)\n"
               "s_barrier" ::: "memory");
}
// consumer barrier: LDS-only drain; its global->reg prefetch stays in flight.
__device__ __forceinline__ void barrier_lgkm() {
  asm volatile("s_waitcnt lgkmcnt(0)\n"
               "s_barrier" ::: "memory");
}

// ============================================================================
// Prep: per (batch, 32-key tile): inv-norms, normalized bf16 K, two images:
//   KA[b][kt][32 k][256 c]: 16B-unit u stored at u ^ (k&7)  (GEMM1 LDS image)
//   KB[b][kt][256 c][32 k]: plain layout                    (GEMM2 L2 image)
// ============================================================================
__global__ __launch_bounds__(256)
void ca_prep(const float* __restrict__ F, __bf16* __restrict__ KA,
             __bf16* __restrict__ KB) {
  const int b   = blockIdx.x;
  const int kt  = blockIdx.y;          // 128 tiles of 32 keys
  const int kt0 = kt * 32;
  const int t   = threadIdx.x;
  const int k   = t & 31;
  const int h   = (t >> 5) & 1;
  const int w   = t >> 6;

  const float* __restrict__ Fb = F + (size_t)b * CH * NPIX;

  __shared__ float red[4][32];
  __shared__ float invk[32];
  __shared__ __align__(16) __bf16 T[32][264];   // +8 pad

  float fv[32];
  float ss = 0.f;
#pragma unroll
  for (int rep = 0; rep < 32; ++rep) {
    int c = rep * 8 + w * 2 + h;
    float v = Fb[(size_t)c * NPIX + kt0 + k] + EPSV;
    fv[rep] = v;
    ss = fmaf(v, v, ss);
  }
  ss += __shfl_xor(ss, 32, 64);
  if ((t & 32) == 0) red[w][k] = ss;
  __syncthreads();
  if (t < 32) invk[t] = rsqrtf(red[0][t] + red[1][t] + red[2][t] + red[3][t]);
  __syncthreads();
  const float iv = invk[k];
#pragma unroll
  for (int rep = 0; rep < 32; ++rep) {
    int c = rep * 8 + w * 2 + h;
    T[k][c] = (__bf16)(fv[rep] * iv);
  }
  __syncthreads();

  // KA image (swizzled for LDS ds_read)
  __bf16* KAp = KA + ((size_t)b * 128 + kt) * (32 * 256);
#pragma unroll
  for (int pass = 0; pass < 4; ++pass) {
    int kk = pass * 8 + (t >> 5);
    int u  = t & 31;
    bf16x8 v = *(const bf16x8*)&T[kk][u * 8];
    *(bf16x8*)&KAp[kk * 256 + ((u ^ (kk & 7)) * 8)] = v;
  }
  // KB image (plain [c][k] for direct coalesced global frag loads)
  __bf16* KBp = KB + ((size_t)b * 128 + kt) * (256 * 32);
#pragma unroll
  for (int pass = 0; pass < 4; ++pass) {
    int c = pass * 64 + (t >> 2);
    int v = t & 3;
    bf16x8 o;
#pragma unroll
    for (int j = 0; j < 8; ++j) o[j] = T[v * 8 + j][c];
    *(bf16x8*)&KBp[c * 32 + v * 8] = o;
  }
}

// ============================================================================
// Fused attention, producer/consumer, counted-vmcnt producer pipeline.
// Grid (8 batch, 64 q-tiles), 512 threads = 8 waves. 130 barriers per role.
//   producer phase i: issue KA(i+2) DMA -> ring buf, GEMM1 on buf(i), softmax,
//                     write P[i&1], barrier vmcnt(4) (vmcnt(0) for i>=126).
//   consumer phase i (i>=1): GEMM2 on tile i-1 (reg set (i-1)&1), issue
//                     KB(i+1) loads, barrier lgkm-only.
// ============================================================================
__global__ __launch_bounds__(512, 4)
void ca_attn6(const float* __restrict__ F, const __bf16* __restrict__ KA,
              const __bf16* __restrict__ KB, float* __restrict__ Out) {
  __shared__ __align__(16) __bf16 KAl[3][32][256];   // 48 KB (ring, 3 tiles)
  __shared__ __align__(16) __bf16 Pl[2][64][32];     //  8 KB (dbuf P)
  __shared__ float lE[2][64];                        // 512 B

  const int tid  = threadIdx.x;
  const int lane = tid & 63;
  const int w    = tid >> 6;            // 0..7
  const int lq   = lane & 15;
  const int lg   = lane >> 4;
  const int b    = blockIdx.x;          // batch fastest -> one batch per XCD
  const int q0   = blockIdx.y * 64;
  const int rsw  = (lq >> 1) & 3;       // shared P swizzle key

  const char* KAb = (const char*)(KA + (size_t)b * (size_t)NPIX * CH);
  const char* KBb = (const char*)(KB + (size_t)b * (size_t)NPIX * CH);

  if (w < 4) {
    // =================== producer: GEMM1 + softmax ========================
    const int kh = w >> 1, qh = w & 1;
    const int qA = q0 + qh * 32 + lq;
    const int qB = qA + 16;
    const float* __restrict__ Fb = F + (size_t)b * CH * NPIX;

    // stage KA(0)->buf0, KA(1)->buf1 first (8 loads in flight, overlap Q load)
    {
      const int wo = w * 4096;
#pragma unroll
      for (int j = 0; j < 4; ++j)
        gload16(KAb + wo + j * 1024 + lane * 16, (char*)KAl[0] + wo + j * 1024);
#pragma unroll
      for (int j = 0; j < 4; ++j)
        gload16(KAb + 16384 + wo + j * 1024 + lane * 16,
                (char*)KAl[1] + wo + j * 1024);
    }

    // Q fragments (pre-scaled by L2E) + squared norms for the fixed shift
    bf16x8 qfA[8], qfB[8];
    float ssA = 0.f, ssB = 0.f;
#pragma unroll
    for (int cf = 0; cf < 8; ++cf) {
#pragma unroll
      for (int j = 0; j < 8; ++j) {
        int c = cf * 32 + lg * 8 + j;
        float va = Fb[(size_t)c * NPIX + qA];
        float vb = Fb[(size_t)c * NPIX + qB];
        qfA[cf][j] = (__bf16)(va * L2E);
        qfB[cf][j] = (__bf16)(vb * L2E);
        ssA = fmaf(va, va, ssA);
        ssB = fmaf(vb, vb, ssB);
      }
    }
    ssA += __shfl_xor(ssA, 16, 64); ssA += __shfl_xor(ssA, 32, 64);
    ssB += __shfl_xor(ssB, 16, 64); ssB += __shfl_xor(ssB, 32, 64);
    // m_q = ||F_q||: provable max of S[:,q] (K rows unit-norm), exact shift.
    const float mqA = sqrtf(ssA) * L2E, mqB = sqrtf(ssB) * L2E;
    // by here the compiler has drained all Q-load vmcnt (ss uses); only the
    // 8 staging DMAs remain outstanding.

    float lA = 0.f, lB = 0.f;
    const int krow = kh * 16 + lq;
    const int ksw  = lq & 7;
    const int pu   = (kh << 1) | (lg >> 1);
    const int pwA  = (qh * 32 + lq) * 32 + (((pu ^ rsw) << 3) + ((lg & 1) << 2));
    const int pwB  = pwA + 16 * 32;
    const int rowB = krow * 512;          // byte offset of krow within a buf

    barrier_vm4();                                   // #1: tile0 landed

    const f32x4 zero = {0.f, 0.f, 0.f, 0.f};
    const char* kanext = KAb + 2 * 16384;  // next tile to stage = tile 2
    int rdOff = 0;                         // ring read offset (bytes)
    const int wo = w * 4096;
    for (int i = 0; i < 128; ++i) {
      const int cb = i & 1;
      if (i < 126) {                       // stage KA(i+2) into ring slot
        int wrOff = rdOff + 2 * 16384;
        if (wrOff >= 3 * 16384) wrOff -= 3 * 16384;
        char* d = (char*)KAl[0] + wrOff + wo;
#pragma unroll
        for (int j = 0; j < 4; ++j)
          gload16(kanext + wo + j * 1024 + lane * 16, d + j * 1024);
        kanext += 16384;
      }

      // GEMM1 on ring slot rdOff; accumulator chains split 4-deep
      const char* abase = (const char*)KAl[0] + rdOff + rowB;
      f32x4 s0a = zero, s0b = zero, s1a = zero, s1b = zero;
      __builtin_amdgcn_s_setprio(1);
#pragma unroll
      for (int cf = 0; cf < 4; ++cf) {
        bf16x8 a = *(const bf16x8*)(abase + ((((cf << 2) | lg) ^ ksw) << 4));
        s0a = __builtin_amdgcn_mfma_f32_16x16x32_bf16(a, qfA[cf], s0a, 0, 0, 0);
        s1a = __builtin_amdgcn_mfma_f32_16x16x32_bf16(a, qfB[cf], s1a, 0, 0, 0);
      }
#pragma unroll
      for (int cf = 4; cf < 8; ++cf) {
        bf16x8 a = *(const bf16x8*)(abase + ((((cf << 2) | lg) ^ ksw) << 4));
        s0b = __builtin_amdgcn_mfma_f32_16x16x32_bf16(a, qfA[cf], s0b, 0, 0, 0);
        s1b = __builtin_amdgcn_mfma_f32_16x16x32_bf16(a, qfB[cf], s1b, 0, 0, 0);
      }
      __builtin_amdgcn_s_setprio(0);
      f32x4 s0 = s0a + s0b;
      f32x4 s1 = s1a + s1b;

      bf16x4 pv0, pv1;
#pragma unroll
      for (int r = 0; r < 4; ++r) {
        float p0 = exp2f(s0[r] - mqA);
        float p1 = exp2f(s1[r] - mqB);
        lA += p0; lB += p1;
        pv0[r] = (__bf16)p0;
        pv1[r] = (__bf16)p1;
      }
      *(bf16x4*)&Pl[cb][0][pwA] = pv0;
      *(bf16x4*)&Pl[cb][0][pwB] = pv1;

      if (i < 126) barrier_vm4();                    // tile i+1 landed
      else         barrier_full();                   // last tiles: full drain
      rdOff += 16384;
      if (rdOff == 3 * 16384) rdOff = 0;
    }

    // phase 128: final softmax denominators -> lE
    lA += __shfl_xor(lA, 16, 64); lA += __shfl_xor(lA, 32, 64);
    lB += __shfl_xor(lB, 16, 64); lB += __shfl_xor(lB, 32, 64);
    if (lg == 0) lE[kh][qh * 32 + lq] = lA;
    if (lg == 1) lE[kh][qh * 32 + 16 + lq] = lB;
    barrier_full();                                  // #130

  } else {
    // =================== consumer: GEMM2 ==================================
    const int cq = w - 4;
    const int c0 = cq * 64;
    const size_t fragBase = (size_t)(c0 + lq) * 64 + (size_t)lg * 16;
    const int prBase = lq * 32 + ((lg ^ rsw) << 3);  // + j*512 for q-frag j

    const f32x4 zero = {0.f, 0.f, 0.f, 0.f};
    f32x4 oacc[4][4];
#pragma unroll
    for (int i = 0; i < 4; ++i)
#pragma unroll
      for (int j = 0; j < 4; ++j) oacc[i][j] = zero;

    bf16x8 a0, a1, a2, a3, b0, b1, b2, b3;   // KB frag reg double-buffer
    const char* kptr = KBb + fragBase;

#define LOAD_KB(R0, R1, R2, R3)                                              \
  do {                                                                       \
    R0 = *(const bf16x8*)(kptr);                                             \
    R1 = *(const bf16x8*)(kptr + 1024);                                      \
    R2 = *(const bf16x8*)(kptr + 2048);                                      \
    R3 = *(const bf16x8*)(kptr + 3072);                                      \
    kptr += 16384;                                                           \
  } while (0)

#define GEMM2_PHASE(K0, K1, K2, K3, PB)                                      \
  do {                                                                       \
    const __bf16* pb_ = &Pl[PB][0][0];                                       \
    bf16x8 pf0 = *(const bf16x8*)&pb_[prBase];                               \
    bf16x8 pf1 = *(const bf16x8*)&pb_[prBase + 16 * 32];                     \
    bf16x8 pf2 = *(const bf16x8*)&pb_[prBase + 32 * 32];                     \
    bf16x8 pf3 = *(const bf16x8*)&pb_[prBase + 48 * 32];                     \
    __builtin_amdgcn_s_setprio(1);                                           \
    oacc[0][0] = __builtin_amdgcn_mfma_f32_16x16x32_bf16(K0, pf0, oacc[0][0], 0, 0, 0); \
    oacc[0][1] = __builtin_amdgcn_mfma_f32_16x16x32_bf16(K0, pf1, oacc[0][1], 0, 0, 0); \
    oacc[0][2] = __builtin_amdgcn_mfma_f32_16x16x32_bf16(K0, pf2, oacc[0][2], 0, 0, 0); \
    oacc[0][3] = __builtin_amdgcn_mfma_f32_16x16x32_bf16(K0, pf3, oacc[0][3], 0, 0, 0); \
    oacc[1][0] = __builtin_amdgcn_mfma_f32_16x16x32_bf16(K1, pf0, oacc[1][0], 0, 0, 0); \
    oacc[1][1] = __builtin_amdgcn_mfma_f32_16x16x32_bf16(K1, pf1, oacc[1][1], 0, 0, 0); \
    oacc[1][2] = __builtin_amdgcn_mfma_f32_16x16x32_bf16(K1, pf2, oacc[1][2], 0, 0, 0); \
    oacc[1][3] = __builtin_amdgcn_mfma_f32_16x16x32_bf16(K1, pf3, oacc[1][3], 0, 0, 0); \
    oacc[2][0] = __builtin_amdgcn_mfma_f32_16x16x32_bf16(K2, pf0, oacc[2][0], 0, 0, 0); \
    oacc[2][1] = __builtin_amdgcn_mfma_f32_16x16x32_bf16(K2, pf1, oacc[2][1], 0, 0, 0); \
    oacc[2][2] = __builtin_amdgcn_mfma_f32_16x16x32_bf16(K2, pf2, oacc[2][2], 0, 0, 0); \
    oacc[2][3] = __builtin_amdgcn_mfma_f32_16x16x32_bf16(K2, pf3, oacc[2][3], 0, 0, 0); \
    oacc[3][0] = __builtin_amdgcn_mfma_f32_16x16x32_bf16(K3, pf0, oacc[3][0], 0, 0, 0); \
    oacc[3][1] = __builtin_amdgcn_mfma_f32_16x16x32_bf16(K3, pf1, oacc[3][1], 0, 0, 0); \
    oacc[3][2] = __builtin_amdgcn_mfma_f32_16x16x32_bf16(K3, pf2, oacc[3][2], 0, 0, 0); \
    oacc[3][3] = __builtin_amdgcn_mfma_f32_16x16x32_bf16(K3, pf3, oacc[3][3], 0, 0, 0); \
    __builtin_amdgcn_s_setprio(0);                                           \
  } while (0)

    LOAD_KB(a0, a1, a2, a3);                         // kb(0) -> A
    barrier_lgkm();                                  // #1
    LOAD_KB(b0, b1, b2, b3);                         // phase 0: kb(1) -> B
    barrier_lgkm();                                  // #2

    for (int ii = 0; ii < 64; ++ii) {
      // phase 2ii+1: tile 2ii with set A, P[0]
      GEMM2_PHASE(a0, a1, a2, a3, 0);
      if (ii < 63) LOAD_KB(a0, a1, a2, a3);          // kb(2ii+2) -> A
      barrier_lgkm();                                // #2ii+3
      // phase 2ii+2: tile 2ii+1 with set B, P[1]
      GEMM2_PHASE(b0, b1, b2, b3, 1);
      if (ii < 63) LOAD_KB(b0, b1, b2, b3);          // kb(2ii+3) -> B
      barrier_lgkm();                                // #2ii+4
    }
#undef LOAD_KB
#undef GEMM2_PHASE

    // epilogue: normalize and store (after barrier #130; lE published)
    float rl0 = 1.0f / (lE[0][0 * 16 + lq] + lE[1][0 * 16 + lq]);
    float rl1 = 1.0f / (lE[0][1 * 16 + lq] + lE[1][1 * 16 + lq]);
    float rl2 = 1.0f / (lE[0][2 * 16 + lq] + lE[1][2 * 16 + lq]);
    float rl3 = 1.0f / (lE[0][3 * 16 + lq] + lE[1][3 * 16 + lq]);
    float* __restrict__ Ob = Out + (size_t)b * CH * NPIX;
#pragma unroll
    for (int ct = 0; ct < 4; ++ct) {
#pragma unroll
      for (int r = 0; r < 4; ++r) {
        const int c = c0 + ct * 16 + lg * 4 + r;
        float* orow = Ob + (size_t)c * NPIX + q0;
        orow[0 * 16 + lq] = oacc[ct][0][r] * rl0;
        orow[1 * 16 + lq] = oacc[ct][1][r] * rl1;
        orow[2 * 16 + lq] = oacc[ct][2][r] * rl2;
        orow[3 * 16 + lq] = oacc[ct][3][r] * rl3;
      }
    }
  }
}

// ============================================================================
extern "C" void kernel_launch(void* const* d_in, const int* in_sizes, int n_in,
                              void* d_out, int out_size, void* d_ws, size_t ws_size,
                              hipStream_t stream) {
  const float* F = (const float*)d_in[0];
  float* out = (float*)d_out;
  const size_t imgElems = (size_t)BATCH * NPIX * CH;   // 8.4M bf16 per image

  __bf16* KAi = (__bf16*)d_ws;            // ws >= 33.6 MB (verified rounds 2-5)
  __bf16* KBi = KAi + imgElems;
  ca_prep<<<dim3(BATCH, 128), 256, 0, stream>>>(F, KAi, KBi);
  ca_attn6<<<dim3(BATCH, 64), 512, 0, stream>>>(F, KAi, KBi, out);
}

// Round 8
// 155.707 us; speedup vs baseline: 1.1434x; 1.1434x over previous
//
#include <hip/hip_runtime.h>

// ContextualAttention: out[b,c,p] = sum_k K[b,k,c] * softmax_k( K[b,:,:] @ F[b,:,p] )
// K = rowwise-normalized (F^T + eps). Flash-style fusion, bf16 MFMA, f32 accum.
// Round 7: fat phases. KT=64 per phase (64 phases, 66 barriers vs 130):
//   amortizes the measured ~1900cyc/phase lockstep overhead over 2x MFMA work.
//   Producer: 4 independent 8-deep MFMA chains, stages 32KB/phase, full-drain.
//   Consumer: kb prefetch issued pre-barrier (full phase to land), lgkm-only
//   barriers; 1 live pf frag to cap VGPR <=128 (16 waves/CU).
//   LDS exactly 80KB: KA dbuf 64K + P dbuf 16K; lE aliased into dead KA[0].

#define BATCH 8
#define CH 256
#define NPIX 4096
#define EPSV 1e-7f
#define L2E 1.4426950408889634f

using bf16x8 = __attribute__((ext_vector_type(8))) __bf16;
using bf16x4 = __attribute__((ext_vector_type(4))) __bf16;
using f32x4  = __attribute__((ext_vector_type(4))) float;

__device__ __forceinline__ void gload16(const void* g, void* l) {
  __builtin_amdgcn_global_load_lds(
      (const __attribute__((address_space(1))) unsigned int*)g,
      (__attribute__((address_space(3))) unsigned int*)l, 16, 0, 0);
}

// producer barrier: full drain (its global_load_lds results are read by OTHER
// producer waves next phase; P writes must be visible).
__device__ __forceinline__ void barrier_full() {
  asm volatile("s_waitcnt vmcnt(0) lgkmcnt(0)\n"
               "s_barrier" ::: "memory");
}
// consumer barrier: LDS-only drain; its global->reg prefetch stays in flight.
__device__ __forceinline__ void barrier_lgkm() {
  asm volatile("s_waitcnt lgkmcnt(0)\n"
               "s_barrier" ::: "memory");
}

// ============================================================================
// Prep: per (batch, 32-key tile): inv-norms, normalized bf16 K, two images:
//   KA[b][kt][32 k][256 c]: 16B-unit u stored at u ^ (k&7)  (GEMM1 LDS image)
//   KB[b][kt][256 c][32 k]: plain layout                    (GEMM2 L2 image)
// ============================================================================
__global__ __launch_bounds__(256)
void ca_prep(const float* __restrict__ F, __bf16* __restrict__ KA,
             __bf16* __restrict__ KB) {
  const int b   = blockIdx.x;
  const int kt  = blockIdx.y;          // 128 tiles of 32 keys
  const int kt0 = kt * 32;
  const int t   = threadIdx.x;
  const int k   = t & 31;
  const int h   = (t >> 5) & 1;
  const int w   = t >> 6;

  const float* __restrict__ Fb = F + (size_t)b * CH * NPIX;

  __shared__ float red[4][32];
  __shared__ float invk[32];
  __shared__ __align__(16) __bf16 T[32][264];   // +8 pad

  float fv[32];
  float ss = 0.f;
#pragma unroll
  for (int rep = 0; rep < 32; ++rep) {
    int c = rep * 8 + w * 2 + h;
    float v = Fb[(size_t)c * NPIX + kt0 + k] + EPSV;
    fv[rep] = v;
    ss = fmaf(v, v, ss);
  }
  ss += __shfl_xor(ss, 32, 64);
  if ((t & 32) == 0) red[w][k] = ss;
  __syncthreads();
  if (t < 32) invk[t] = rsqrtf(red[0][t] + red[1][t] + red[2][t] + red[3][t]);
  __syncthreads();
  const float iv = invk[k];
#pragma unroll
  for (int rep = 0; rep < 32; ++rep) {
    int c = rep * 8 + w * 2 + h;
    T[k][c] = (__bf16)(fv[rep] * iv);
  }
  __syncthreads();

  // KA image (swizzled for LDS ds_read)
  __bf16* KAp = KA + ((size_t)b * 128 + kt) * (32 * 256);
#pragma unroll
  for (int pass = 0; pass < 4; ++pass) {
    int kk = pass * 8 + (t >> 5);
    int u  = t & 31;
    bf16x8 v = *(const bf16x8*)&T[kk][u * 8];
    *(bf16x8*)&KAp[kk * 256 + ((u ^ (kk & 7)) * 8)] = v;
  }
  // KB image (plain [c][k] for direct coalesced global frag loads)
  __bf16* KBp = KB + ((size_t)b * 128 + kt) * (256 * 32);
#pragma unroll
  for (int pass = 0; pass < 4; ++pass) {
    int c = pass * 64 + (t >> 2);
    int v = t & 3;
    bf16x8 o;
#pragma unroll
    for (int j = 0; j < 8; ++j) o[j] = T[v * 8 + j][c];
    *(bf16x8*)&KBp[c * 32 + v * 8] = o;
  }
}

// ============================================================================
// Fused attention, producer/consumer, KT=64 fat phases.
// Grid (8 batch, 64 q-tiles), 512 threads = 8 waves. 66 barriers per role.
// smem layout (80KB exact):
//   [0, 64K)  KA dbuf: buf cb at cb*32768, each = 2 sub-tiles of 16KB
//             (32 k x 256 c, 16B-unit u at u^(k&7), 512B rows)
//   [64K,80K) P dbuf:  buf pb at 64K + pb*8192, P[64 q][64 k] bf16,
//             128B rows, 16B-unit u at u^(q&7)
//   lE[2][64] floats aliased at smem+0 (KA buf0 dead after phase 62).
// ============================================================================
__global__ __launch_bounds__(512, 4)
void ca_attn7(const float* __restrict__ F, const __bf16* __restrict__ KA,
              const __bf16* __restrict__ KB, float* __restrict__ Out) {
  __shared__ __align__(16) char smem[81920];

  const int tid  = threadIdx.x;
  const int lane = tid & 63;
  const int w    = tid >> 6;            // 0..7
  const int lq   = lane & 15;
  const int lg   = lane >> 4;
  const int b    = blockIdx.x;          // batch fastest -> one batch per XCD
  const int q0   = blockIdx.y * 64;

  const char* KAb = (const char*)(KA + (size_t)b * (size_t)NPIX * CH);
  const char* KBb = (const char*)(KB + (size_t)b * (size_t)NPIX * CH);
  char* PlB = smem + 65536;

  if (w < 4) {
    // =================== producer: GEMM1 + softmax ========================
    const int kh = w >> 1, qh = w & 1;
    const int qA = q0 + qh * 32 + lq;
    const int qB = qA + 16;
    const float* __restrict__ Fb = F + (size_t)b * CH * NPIX;
    const int wo = w * 8192;            // this wave's 8KB slice of a 32KB tile

    // stage tile 0 -> buf 0 (overlaps Q loads below)
#pragma unroll
    for (int j = 0; j < 8; ++j)
      gload16(KAb + wo + j * 1024 + lane * 16, smem + wo + j * 1024);

    // Q fragments (pre-scaled by L2E) + squared norms for the fixed shift
    bf16x8 qfA[8], qfB[8];
    float ssA = 0.f, ssB = 0.f;
#pragma unroll
    for (int cf = 0; cf < 8; ++cf) {
#pragma unroll
      for (int j = 0; j < 8; ++j) {
        int c = cf * 32 + lg * 8 + j;
        float va = Fb[(size_t)c * NPIX + qA];
        float vb = Fb[(size_t)c * NPIX + qB];
        qfA[cf][j] = (__bf16)(va * L2E);
        qfB[cf][j] = (__bf16)(vb * L2E);
        ssA = fmaf(va, va, ssA);
        ssB = fmaf(vb, vb, ssB);
      }
    }
    ssA += __shfl_xor(ssA, 16, 64); ssA += __shfl_xor(ssA, 32, 64);
    ssB += __shfl_xor(ssB, 16, 64); ssB += __shfl_xor(ssB, 32, 64);
    // m_q = ||F_q||: provable max of S[:,q] (K rows unit-norm), exact shift.
    const float mqA = sqrtf(ssA) * L2E, mqB = sqrtf(ssB) * L2E;

    float lA = 0.f, lB = 0.f;
    const int krow = kh * 16 + lq;      // A row within each 32k sub-tile
    const int ksw  = lq & 7;
    const int rowByte = krow * 512;
    // P write offsets: row q, unit u = s*4 + kh*2 + (lg>>1), u^=(q&7)=lq&7,
    // + (lg&1)*8 bytes within unit.  (q = qh*32 + qf*16 + lq)
    const int pwRowA = (qh * 32 + lq) * 128;
    const int pwRowB = (qh * 32 + 16 + lq) * 128;
    const int puBase = kh * 2 + (lg >> 1);
    const int pwSub  = ((lg & 1) << 3);

    barrier_full();                                  // #1: tile 0 landed

    const f32x4 zero = {0.f, 0.f, 0.f, 0.f};
    for (int i = 0; i < 64; ++i) {
      const int cb = i & 1;
      if (i < 63) {                                  // stage tile i+1
        const char* s = KAb + (size_t)(i + 1) * 32768;
        char* d = smem + (cb ^ 1) * 32768;
#pragma unroll
        for (int j = 0; j < 8; ++j)
          gload16(s + wo + j * 1024 + lane * 16, d + wo + j * 1024);
      }

      // GEMM1: 4 independent 8-deep chains (2 sub-tiles x 2 q-frags)
      const char* ab0 = smem + cb * 32768 + rowByte;          // sub-tile 0
      const char* ab1 = ab0 + 16384;                          // sub-tile 1
      f32x4 s00 = zero, s01 = zero, s10 = zero, s11 = zero;
      __builtin_amdgcn_s_setprio(1);
#pragma unroll
      for (int cf = 0; cf < 8; ++cf) {
        const int uo = ((((cf << 2) | lg) ^ ksw) << 4);
        bf16x8 a0 = *(const bf16x8*)(ab0 + uo);
        bf16x8 a1 = *(const bf16x8*)(ab1 + uo);
        s00 = __builtin_amdgcn_mfma_f32_16x16x32_bf16(a0, qfA[cf], s00, 0, 0, 0);
        s01 = __builtin_amdgcn_mfma_f32_16x16x32_bf16(a0, qfB[cf], s01, 0, 0, 0);
        s10 = __builtin_amdgcn_mfma_f32_16x16x32_bf16(a1, qfA[cf], s10, 0, 0, 0);
        s11 = __builtin_amdgcn_mfma_f32_16x16x32_bf16(a1, qfB[cf], s11, 0, 0, 0);
      }
      __builtin_amdgcn_s_setprio(0);

      // softmax numerators (fixed shift), write P
      char* pb = PlB + cb * 8192;
      bf16x4 pv00, pv01, pv10, pv11;
#pragma unroll
      for (int r = 0; r < 4; ++r) {
        float p00 = exp2f(s00[r] - mqA);
        float p01 = exp2f(s01[r] - mqB);
        float p10 = exp2f(s10[r] - mqA);
        float p11 = exp2f(s11[r] - mqB);
        lA += p00 + p10; lB += p01 + p11;
        pv00[r] = (__bf16)p00; pv01[r] = (__bf16)p01;
        pv10[r] = (__bf16)p10; pv11[r] = (__bf16)p11;
      }
      {
        const int u0 = (puBase ^ ksw) << 4;          // sub-tile 0 unit
        const int u1 = ((4 + puBase) ^ ksw) << 4;    // sub-tile 1 unit
        *(bf16x4*)(pb + pwRowA + u0 + pwSub) = pv00;
        *(bf16x4*)(pb + pwRowB + u0 + pwSub) = pv01;
        *(bf16x4*)(pb + pwRowA + u1 + pwSub) = pv10;
        *(bf16x4*)(pb + pwRowB + u1 + pwSub) = pv11;
      }

      barrier_full();                                // #i+2
    }

    // final softmax denominators -> lE (aliased at smem+0; KA buf0 is dead)
    lA += __shfl_xor(lA, 16, 64); lA += __shfl_xor(lA, 32, 64);
    lB += __shfl_xor(lB, 16, 64); lB += __shfl_xor(lB, 32, 64);
    float* lE = (float*)smem;
    if (lg == 0) lE[kh * 64 + qh * 32 + lq] = lA;
    if (lg == 1) lE[kh * 64 + qh * 32 + 16 + lq] = lB;
    barrier_full();                                  // #66

  } else {
    // =================== consumer: GEMM2 ==================================
    const int cq = w - 4;
    const int c0 = cq * 64;
    const size_t fragBase = (size_t)(c0 + lq) * 64 + (size_t)lg * 16;
    // pf read: row = qf*16+lq, unit u = ks2*4+lg, u ^= (lq&7)
    const int prRow = lq * 128;
    const int prU0  = ((0 * 4 + lg) ^ (lq & 7)) << 4;   // ks2=0
    const int prU1  = ((1 * 4 + lg) ^ (lq & 7)) << 4;   // ks2=1

    const f32x4 zero = {0.f, 0.f, 0.f, 0.f};
    f32x4 oacc[4][4];
#pragma unroll
    for (int i = 0; i < 4; ++i)
#pragma unroll
      for (int j = 0; j < 4; ++j) oacc[i][j] = zero;

    barrier_lgkm();                                  // #1

    for (int jt = 0; jt < 64; ++jt) {
      // issue KB frag loads for tile jt (full phase to land across barrier)
      const char* kb0 = KBb + (size_t)(2 * jt) * 16384 + fragBase;
      const char* kb1 = kb0 + 16384;
      bf16x8 k00 = *(const bf16x8*)(kb0);
      bf16x8 k01 = *(const bf16x8*)(kb0 + 1024);
      bf16x8 k02 = *(const bf16x8*)(kb0 + 2048);
      bf16x8 k03 = *(const bf16x8*)(kb0 + 3072);
      bf16x8 k10 = *(const bf16x8*)(kb1);
      bf16x8 k11 = *(const bf16x8*)(kb1 + 1024);
      bf16x8 k12 = *(const bf16x8*)(kb1 + 2048);
      bf16x8 k13 = *(const bf16x8*)(kb1 + 3072);

      barrier_lgkm();                                // #jt+2: P(jt) ready

      const char* pb = PlB + (jt & 1) * 8192;
      __builtin_amdgcn_s_setprio(1);
#pragma unroll
      for (int qf = 0; qf < 4; ++qf) {
        bf16x8 pf0 = *(const bf16x8*)(pb + prRow + qf * 2048 + prU0);
        oacc[0][qf] = __builtin_amdgcn_mfma_f32_16x16x32_bf16(k00, pf0, oacc[0][qf], 0, 0, 0);
        oacc[1][qf] = __builtin_amdgcn_mfma_f32_16x16x32_bf16(k01, pf0, oacc[1][qf], 0, 0, 0);
        oacc[2][qf] = __builtin_amdgcn_mfma_f32_16x16x32_bf16(k02, pf0, oacc[2][qf], 0, 0, 0);
        oacc[3][qf] = __builtin_amdgcn_mfma_f32_16x16x32_bf16(k03, pf0, oacc[3][qf], 0, 0, 0);
      }
#pragma unroll
      for (int qf = 0; qf < 4; ++qf) {
        bf16x8 pf1 = *(const bf16x8*)(pb + prRow + qf * 2048 + prU1);
        oacc[0][qf] = __builtin_amdgcn_mfma_f32_16x16x32_bf16(k10, pf1, oacc[0][qf], 0, 0, 0);
        oacc[1][qf] = __builtin_amdgcn_mfma_f32_16x16x32_bf16(k11, pf1, oacc[1][qf], 0, 0, 0);
        oacc[2][qf] = __builtin_amdgcn_mfma_f32_16x16x32_bf16(k12, pf1, oacc[2][qf], 0, 0, 0);
        oacc[3][qf] = __builtin_amdgcn_mfma_f32_16x16x32_bf16(k13, pf1, oacc[3][qf], 0, 0, 0);
      }
      __builtin_amdgcn_s_setprio(0);
    }

    barrier_lgkm();                                  // #66: lE published

    // epilogue: normalize and store
    const float* lE = (const float*)smem;
    float rl0 = 1.0f / (lE[0 * 16 + lq] + lE[64 + 0 * 16 + lq]);
    float rl1 = 1.0f / (lE[1 * 16 + lq] + lE[64 + 1 * 16 + lq]);
    float rl2 = 1.0f / (lE[2 * 16 + lq] + lE[64 + 2 * 16 + lq]);
    float rl3 = 1.0f / (lE[3 * 16 + lq] + lE[64 + 3 * 16 + lq]);
    float* __restrict__ Ob = Out + (size_t)b * CH * NPIX;
#pragma unroll
    for (int ct = 0; ct < 4; ++ct) {
#pragma unroll
      for (int r = 0; r < 4; ++r) {
        const int c = c0 + ct * 16 + lg * 4 + r;
        float* orow = Ob + (size_t)c * NPIX + q0;
        orow[0 * 16 + lq] = oacc[ct][0][r] * rl0;
        orow[1 * 16 + lq] = oacc[ct][1][r] * rl1;
        orow[2 * 16 + lq] = oacc[ct][2][r] * rl2;
        orow[3 * 16 + lq] = oacc[ct][3][r] * rl3;
      }
    }
  }
}

// ============================================================================
extern "C" void kernel_launch(void* const* d_in, const int* in_sizes, int n_in,
                              void* d_out, int out_size, void* d_ws, size_t ws_size,
                              hipStream_t stream) {
  const float* F = (const float*)d_in[0];
  float* out = (float*)d_out;
  const size_t imgElems = (size_t)BATCH * NPIX * CH;   // 8.4M bf16 per image

  __bf16* KAi = (__bf16*)d_ws;            // ws >= 33.6 MB (verified rounds 2-6)
  __bf16* KBi = KAi + imgElems;
  ca_prep<<<dim3(BATCH, 128), 256, 0, stream>>>(F, KAi, KBi);
  ca_attn7<<<dim3(BATCH, 64), 512, 0, stream>>>(F, KAi, KBi, out);
}